// Round 1
// baseline (352.233 us; speedup 1.0000x reference)
//
#include <hip/hip_runtime.h>
#include <climits>

#define T_STEPS 1024
#define B_SZ    1024
#define N_NEUR  64
#define BETA    0.9f
#define THRESH  1.0f

// ws layout: ws_int[0] = Tstar (first global readout fire step), ws_int[1] = winner key (t*64 | n)

__global__ __launch_bounds__(64) void k_init(int* __restrict__ ws) {
  if (threadIdx.x == 0) { ws[0] = INT_MAX; ws[1] = INT_MAX; }
}

// Phase 1: uninhibited sim, find Tstar and winner key. 1 wave = 1 batch element, lane = neuron.
__global__ __launch_bounds__(256) void k_phase1(
    const float* __restrict__ x, const float* __restrict__ W,
    int* __restrict__ ws)
{
  const int lane = threadIdx.x & 63;
  const int b = blockIdx.x * 4 + (threadIdx.x >> 6);
  const float w1 = W[lane * 2 + 0];
  const float w2 = W[lane * 2 + 1];
  float mem = 0.0f, ro = 0.0f;
  int tfire = INT_MAX, key = INT_MAX;
  for (int t0 = 0; t0 < T_STEPS; t0 += 64) {
    // lane l prefetches x[t0+l, b, :]; broadcast per-step via shfl
    const float2 xv = *reinterpret_cast<const float2*>(x + ((size_t)(t0 + lane) * B_SZ + b) * 2);
    #pragma unroll
    for (int i = 0; i < 64; ++i) {
      const float x0 = __shfl(xv.x, i);
      const float x1 = __shfl(xv.y, i);
      // cur exact for x in {0,1}; recurrence must be non-fused to match numpy order
      const float cur = __fadd_rn(__fmul_rn(x0, w1), __fmul_rn(x1, w2));
      const float rst = (mem > THRESH) ? THRESH : 0.0f;
      mem = __fsub_rn(__fadd_rn(__fmul_rn(BETA, mem), cur), rst);
      const unsigned long long msk = __ballot(mem > THRESH);
      if (key == INT_MAX && msk)
        key = ((t0 + i) << 6) | (int)__builtin_ctzll(msk);
      const float rocur = (float)__popcll(msk);
      const float rrst = (ro > THRESH) ? THRESH : 0.0f;
      ro = __fsub_rn(__fadd_rn(__fmul_rn(BETA, ro), rocur), rrst);
      if (tfire == INT_MAX && ro > THRESH) tfire = t0 + i;
    }
    if (tfire != INT_MAX && key != INT_MAX) break;  // wave-uniform
  }
  if (lane == 0) { atomicMin(&ws[0], tfire); atomicMin(&ws[1], key); }
}

// Phase 2: re-sim writing bank spikes for t <= Tstop, readout spikes for all t (decay after Tstar).
__global__ __launch_bounds__(256) void k_phase2(
    const float* __restrict__ x, const float* __restrict__ W,
    const int* __restrict__ ws, float* __restrict__ out)
{
  const int lane = threadIdx.x & 63;
  const int b = blockIdx.x * 4 + (threadIdx.x >> 6);
  const int Tstar = ws[0];
  const int Tstop = (Tstar < T_STEPS - 1) ? Tstar : (T_STEPS - 1);
  float* __restrict__ outro = out + (size_t)T_STEPS * B_SZ * N_NEUR;
  const float w1 = W[lane * 2 + 0];
  const float w2 = W[lane * 2 + 1];
  float mem = 0.0f, ro = 0.0f;
  for (int t0 = 0; t0 < T_STEPS; t0 += 64) {
    float2 xv = make_float2(0.0f, 0.0f);
    if (t0 <= Tstop)
      xv = *reinterpret_cast<const float2*>(x + ((size_t)(t0 + lane) * B_SZ + b) * 2);
    float myro = 0.0f;
    #pragma unroll 8
    for (int i = 0; i < 64; ++i) {
      const int t = t0 + i;
      float rocur = 0.0f;  // after Tstop: spikes masked -> readout current 0 (pure decay)
      if (t <= Tstop) {    // wave-uniform branch
        const float x0 = __shfl(xv.x, i);
        const float x1 = __shfl(xv.y, i);
        const float cur = __fadd_rn(__fmul_rn(x0, w1), __fmul_rn(x1, w2));
        const float rst = (mem > THRESH) ? THRESH : 0.0f;
        mem = __fsub_rn(__fadd_rn(__fmul_rn(BETA, mem), cur), rst);
        const bool s = mem > THRESH;
        out[((size_t)t * B_SZ + b) * N_NEUR + lane] = s ? 1.0f : 0.0f;
        rocur = (float)__popcll(__ballot(s));
      }
      // matches ref exactly: ((BETA*ro) + rocur) - rrst, rocur possibly +0.0
      const float rrst = (ro > THRESH) ? THRESH : 0.0f;
      ro = __fsub_rn(__fadd_rn(__fmul_rn(BETA, ro), rocur), rrst);
      const float rospk = (ro > THRESH) ? 1.0f : 0.0f;
      myro = (i == lane) ? rospk : myro;  // lane l captures step t0+l
    }
    outro[(size_t)(t0 + lane) * B_SZ + b] = myro;  // one batched (scattered) store per chunk
  }
  if (blockIdx.x == 0 && threadIdx.x == 0) {
    const int key = ws[1];
    float* sc = outro + (size_t)T_STEPS * B_SZ;
    sc[0] = (Tstar < T_STEPS) ? (float)Tstar : -1.0f;  // inhibit_time
    sc[1] = (key != INT_MAX) ? (float)(key & 63) : -1.0f;  // winner
  }
}

// Phase 3: zero-fill bank spike rows for t > Tstar (output is poisoned each call).
__global__ __launch_bounds__(256) void k_fill(const int* __restrict__ ws, float4* __restrict__ out4) {
  const int Tstar = ws[0];
  const size_t n4 = (size_t)T_STEPS * B_SZ * N_NEUR / 4;  // 16,777,216
  const size_t stride = (size_t)gridDim.x * blockDim.x;
  for (size_t i = (size_t)blockIdx.x * blockDim.x + threadIdx.x; i < n4; i += stride) {
    const int t = (int)(i >> 14);  // 16384 float4 per timestep slab (B*N/4)
    if (t > Tstar) out4[i] = make_float4(0.0f, 0.0f, 0.0f, 0.0f);
  }
}

extern "C" void kernel_launch(void* const* d_in, const int* in_sizes, int n_in,
                              void* d_out, int out_size, void* d_ws, size_t ws_size,
                              hipStream_t stream) {
  const float* x = (const float*)d_in[0];   // spike_seq [T,B,2] f32
  const float* W = (const float*)d_in[1];   // W [N,2] f32
  // d_in[2] (delays) unused: delays = 1..N strictly increasing -> winner = min active lane
  float* out = (float*)d_out;
  int* ws = (int*)d_ws;
  k_init  <<<1,        64, 0, stream>>>(ws);
  k_phase1<<<B_SZ / 4, 256, 0, stream>>>(x, W, ws);
  k_phase2<<<B_SZ / 4, 256, 0, stream>>>(x, W, ws, out);
  k_fill  <<<2048,     256, 0, stream>>>(ws, (float4*)out);
}

// Round 4
// 311.441 us; speedup vs baseline: 1.1310x; 1.1310x over previous
//
#include <hip/hip_runtime.h>

#define T_STEPS 1024
#define B_SZ    1024
#define N_NEUR  64
#define SENT    0x7F7F7F7F   // memset(0x7F) sentinel; > any valid key (max 65535) / t (max 1023)

typedef unsigned long long u64;

// ws[0] = Tstar (first global readout-fire step), ws[1] = winner key (t<<6 | n)

// Phase 1: uninhibited sim; find global Tstar and winner key. 1 wave = 1 batch element, lane = neuron.
// Input handled as bitmasks: lane l loads x[t0+l][b], two ballots give 64 steps of input as scalar u64.
__global__ __launch_bounds__(64) void k_phase1(
    const float* __restrict__ x, const float* __restrict__ W, int* __restrict__ ws)
{
  const int lane = threadIdx.x;
  const int b = blockIdx.x;
  const float w1 = W[lane * 2 + 0];
  const float w2 = W[lane * 2 + 1];
  float mem = 0.0f, ro = 0.0f;
  int tfire = SENT, key = SENT;
  for (int c = 0; c < 16; ++c) {
    const int t0 = c << 6;
    const float2 v = *reinterpret_cast<const float2*>(x + ((size_t)(t0 + lane) * B_SZ + b) * 2);
    const u64 m0 = __ballot(v.x != 0.0f);   // x0 bits for steps t0..t0+63 (wave-uniform)
    const u64 m1 = __ballot(v.y != 0.0f);
    #pragma unroll
    for (int i = 0; i < 64; ++i) {
      // cur = fadd(fmul(x0,w1), fmul(x1,w2)) with x in {0,1}  ==  select form, bit-exact
      const float cur = __fadd_rn(((m0 >> i) & 1) ? w1 : 0.0f, ((m1 >> i) & 1) ? w2 : 0.0f);
      const float rst = (mem > 1.0f) ? 1.0f : 0.0f;
      mem = __fsub_rn(__fadd_rn(__fmul_rn(0.9f, mem), cur), rst);
      const u64 msk = __ballot(mem > 1.0f);
      if (key == SENT && msk) key = ((t0 + i) << 6) | (int)__builtin_ctzll(msk);
      const float rocur = (float)__popcll(msk);
      const float rrst = (ro > 1.0f) ? 1.0f : 0.0f;
      ro = __fsub_rn(__fadd_rn(__fmul_rn(0.9f, ro), rocur), rrst);
      if (tfire == SENT && ro > 1.0f) tfire = t0 + i;
    }
    // push own results, poll global minima; break when future steps can no longer win either race
    int o0 = SENT, o1 = SENT;
    if (lane == 0) { o0 = atomicMin(&ws[0], tfire); o1 = atomicMin(&ws[1], key); }
    o0 = __shfl(o0, 0); o1 = __shfl(o1, 0);
    const int nt0 = (c + 1) << 6;
    const bool done_t = (tfire != SENT) || (min(o0, tfire) < nt0);
    const bool done_k = (key  != SENT) || (min(o1, key)  < (nt0 << 6));
    if (done_t && done_k) break;
  }
}

// Fill: zero bank-spike rows with t > Tstar, the ENTIRE readout-spike region, and write the 2 scalars.
__global__ __launch_bounds__(256) void k_fill(const int* __restrict__ ws, float* __restrict__ out)
{
  const int Tstar = ws[0];
  float4* out4 = (float4*)out;
  const size_t n4_bank = (size_t)T_STEPS * B_SZ * N_NEUR / 4;          // 16,777,216
  const size_t n4_tot  = n4_bank + (size_t)T_STEPS * B_SZ / 4;         // + ro region
  const size_t stride = (size_t)gridDim.x * blockDim.x;
  for (size_t i = (size_t)blockIdx.x * blockDim.x + threadIdx.x; i < n4_tot; i += stride) {
    if (i >= n4_bank || (int)(i >> 14) > Tstar)   // 16384 float4 per timestep slab (B*N/4)
      out4[i] = make_float4(0.0f, 0.0f, 0.0f, 0.0f);
  }
  if (blockIdx.x == 0 && threadIdx.x == 0) {
    const int key = ws[1];
    float* sc = out + (size_t)T_STEPS * B_SZ * N_NEUR + (size_t)T_STEPS * B_SZ;
    sc[0] = (Tstar < T_STEPS) ? (float)Tstar : -1.0f;   // inhibit_time
    sc[1] = (key != SENT) ? (float)(key & 63) : -1.0f;  // winner
  }
}

// Phase 2: re-sim t <= Tstop writing bank spikes; continue readout decay, writing only the 1.0s
// (region pre-zeroed by k_fill); break once past Tstop with ro <= threshold (no future spikes).
__global__ __launch_bounds__(64) void k_phase2(
    const float* __restrict__ x, const float* __restrict__ W,
    const int* __restrict__ ws, float* __restrict__ out)
{
  const int lane = threadIdx.x;
  const int b = blockIdx.x;
  const int Tstar = ws[0];
  const int Tstop = (Tstar < T_STEPS - 1) ? Tstar : (T_STEPS - 1);
  float* __restrict__ outro = out + (size_t)T_STEPS * B_SZ * N_NEUR;
  const float w1 = W[lane * 2 + 0];
  const float w2 = W[lane * 2 + 1];
  float mem = 0.0f, ro = 0.0f;
  const int lastc = Tstop >> 6;
  for (int c = 0; c < 16; ++c) {
    const int t0 = c << 6;
    u64 m0 = 0, m1 = 0;
    if (c <= lastc) {
      const float2 v = *reinterpret_cast<const float2*>(x + ((size_t)(t0 + lane) * B_SZ + b) * 2);
      m0 = __ballot(v.x != 0.0f);
      m1 = __ballot(v.y != 0.0f);
    }
    u64 romask = 0;
    #pragma unroll
    for (int i = 0; i < 64; ++i) {
      const int t = t0 + i;
      float rocur = 0.0f;            // after Tstop: spikes inhibited -> readout current 0
      if (t <= Tstop) {              // wave-uniform branch
        const float cur = __fadd_rn(((m0 >> i) & 1) ? w1 : 0.0f, ((m1 >> i) & 1) ? w2 : 0.0f);
        const float rst = (mem > 1.0f) ? 1.0f : 0.0f;
        mem = __fsub_rn(__fadd_rn(__fmul_rn(0.9f, mem), cur), rst);
        const bool s = mem > 1.0f;
        out[((size_t)t * B_SZ + b) * N_NEUR + lane] = s ? 1.0f : 0.0f;  // coalesced 256B wave-store
        rocur = (float)__popcll(__ballot(s));
      }
      const float rrst = (ro > 1.0f) ? 1.0f : 0.0f;
      ro = __fsub_rn(__fadd_rn(__fmul_rn(0.9f, ro), rocur), rrst);
      romask |= (u64)(ro > 1.0f) << i;   // ro is replicated across lanes (wave-uniform)
    }
    if ((romask >> lane) & 1)
      outro[(size_t)(t0 + lane) * B_SZ + b] = 1.0f;   // sparse: only the spikes
    if (t0 + 64 > Tstop && !(ro > 1.0f)) break;       // past Tstop and subthreshold: all-zero from here
  }
}

extern "C" void kernel_launch(void* const* d_in, const int* in_sizes, int n_in,
                              void* d_out, int out_size, void* d_ws, size_t ws_size,
                              hipStream_t stream) {
  const float* x = (const float*)d_in[0];   // spike_seq [T,B,2] f32
  const float* W = (const float*)d_in[1];   // W [N,2] f32
  // d_in[2] (delays) unused: delays = 1..N strictly increasing -> winner = min active lane
  float* out = (float*)d_out;
  int* ws = (int*)d_ws;
  hipMemsetAsync(ws, 0x7F, 8, stream);      // ws[0..1] = SENT (graph-capturable)
  k_phase1<<<B_SZ, 64, 0, stream>>>(x, W, ws);
  k_fill  <<<2048, 256, 0, stream>>>(ws, out);
  k_phase2<<<B_SZ, 64, 0, stream>>>(x, W, ws, out);
}

// Round 5
// 303.665 us; speedup vs baseline: 1.1599x; 1.0256x over previous
//
#include <hip/hip_runtime.h>

#define T_STEPS 1024
#define B_SZ    1024
#define N_NEUR  64
#define SENT    0x7F7F7F7F   // memset(0x7F) sentinel; > any valid key (max 65535) / t (max 1023)

typedef unsigned long long u64;

// ws[0] = Tstar (first global readout-fire step), ws[1] = winner key (t<<6 | n)

// Phase 1: uninhibited sim; find global Tstar and winner key. 1 wave = 1 batch element, lane = neuron.
// Input handled as bitmasks: lane l loads x[t0+l][b], two ballots give 64 steps of input as scalar u64.
__global__ __launch_bounds__(64) void k_phase1(
    const float* __restrict__ x, const float* __restrict__ W, int* __restrict__ ws)
{
  const int lane = threadIdx.x;
  const int b = blockIdx.x;
  const float w1 = W[lane * 2 + 0];
  const float w2 = W[lane * 2 + 1];
  float mem = 0.0f, ro = 0.0f;
  int tfire = SENT, key = SENT;
  for (int c = 0; c < 16; ++c) {
    const int t0 = c << 6;
    const float2 v = *reinterpret_cast<const float2*>(x + ((size_t)(t0 + lane) * B_SZ + b) * 2);
    const u64 m0 = __ballot(v.x != 0.0f);   // x0 bits for steps t0..t0+63 (wave-uniform)
    const u64 m1 = __ballot(v.y != 0.0f);
    #pragma unroll
    for (int i = 0; i < 64; ++i) {
      // cur = fadd(fmul(x0,w1), fmul(x1,w2)) with x in {0,1}  ==  select form, bit-exact
      const float cur = __fadd_rn(((m0 >> i) & 1) ? w1 : 0.0f, ((m1 >> i) & 1) ? w2 : 0.0f);
      const float rst = (mem > 1.0f) ? 1.0f : 0.0f;
      mem = __fsub_rn(__fadd_rn(__fmul_rn(0.9f, mem), cur), rst);
      const u64 msk = __ballot(mem > 1.0f);
      if (key == SENT && msk) key = ((t0 + i) << 6) | (int)__builtin_ctzll(msk);
      const float rocur = (float)__popcll(msk);
      const float rrst = (ro > 1.0f) ? 1.0f : 0.0f;
      ro = __fsub_rn(__fadd_rn(__fmul_rn(0.9f, ro), rocur), rrst);
      if (tfire == SENT && ro > 1.0f) tfire = t0 + i;
    }
    // push own results, poll global minima; break when future steps can no longer win either race
    int o0 = SENT, o1 = SENT;
    if (lane == 0) { o0 = atomicMin(&ws[0], tfire); o1 = atomicMin(&ws[1], key); }
    o0 = __shfl(o0, 0); o1 = __shfl(o1, 0);
    const int nt0 = (c + 1) << 6;
    const bool done_t = (tfire != SENT) || (min(o0, tfire) < nt0);
    const bool done_k = (key  != SENT) || (min(o1, key)  < (nt0 << 6));
    if (done_t && done_k) break;
  }
}

// Finish (fused fill + phase2):
//  part A (wave 0 of blocks 0..1023): re-sim t <= Tstop writing bank spikes (rows t <= Tstar),
//          DENSE readout-spike writes (0s and 1s) with a store-only zero tail after early break,
//          plus the 2 scalars. Bank rows it writes are disjoint from part B's (t <= Tstar vs >).
//  part B (all 2048x256 threads): grid-stride zero-fill of bank rows t > Tstar.
__global__ __launch_bounds__(256) void k_finish(
    const float* __restrict__ x, const float* __restrict__ W,
    const int* __restrict__ ws, float* __restrict__ out)
{
  const int Tstar = ws[0];

  if (blockIdx.x < B_SZ && threadIdx.x < 64) {
    const int lane = threadIdx.x;
    const int b = blockIdx.x;
    const int Tstop = (Tstar < T_STEPS - 1) ? Tstar : (T_STEPS - 1);
    float* __restrict__ outro = out + (size_t)T_STEPS * B_SZ * N_NEUR;
    const float w1 = W[lane * 2 + 0];
    const float w2 = W[lane * 2 + 1];
    float mem = 0.0f, ro = 0.0f;
    const int lastc = Tstop >> 6;
    int c = 0;
    for (; c < 16; ++c) {
      const int t0 = c << 6;
      u64 m0 = 0, m1 = 0;
      if (c <= lastc) {
        const float2 v = *reinterpret_cast<const float2*>(x + ((size_t)(t0 + lane) * B_SZ + b) * 2);
        m0 = __ballot(v.x != 0.0f);
        m1 = __ballot(v.y != 0.0f);
      }
      u64 romask = 0;
      #pragma unroll
      for (int i = 0; i < 64; ++i) {
        const int t = t0 + i;
        float rocur = 0.0f;            // after Tstop: spikes inhibited -> readout current 0
        if (t <= Tstop) {              // wave-uniform branch
          const float cur = __fadd_rn(((m0 >> i) & 1) ? w1 : 0.0f, ((m1 >> i) & 1) ? w2 : 0.0f);
          const float rst = (mem > 1.0f) ? 1.0f : 0.0f;
          mem = __fsub_rn(__fadd_rn(__fmul_rn(0.9f, mem), cur), rst);
          const bool s = mem > 1.0f;
          out[((size_t)t * B_SZ + b) * N_NEUR + lane] = s ? 1.0f : 0.0f;  // coalesced 256B wave-store
          rocur = (float)__popcll(__ballot(s));
        }
        const float rrst = (ro > 1.0f) ? 1.0f : 0.0f;
        ro = __fsub_rn(__fadd_rn(__fmul_rn(0.9f, ro), rocur), rrst);
        romask |= (u64)(ro > 1.0f) << i;   // ro is replicated across lanes (wave-uniform)
      }
      outro[(size_t)(t0 + lane) * B_SZ + b] = ((romask >> lane) & 1) ? 1.0f : 0.0f;  // dense
      if (t0 + 64 > Tstop && !(ro > 1.0f)) { ++c; break; }  // no future ro spikes possible
    }
    for (; c < 16; ++c)                      // store-only zero tail (no FP chain)
      outro[(size_t)((c << 6) + lane) * B_SZ + b] = 0.0f;
    if (blockIdx.x == 0 && threadIdx.x == 0) {
      const int key = ws[1];
      float* sc = outro + (size_t)T_STEPS * B_SZ;
      sc[0] = (Tstar < T_STEPS) ? (float)Tstar : -1.0f;   // inhibit_time
      sc[1] = (key != SENT) ? (float)(key & 63) : -1.0f;  // winner
    }
  }

  // part B: zero bank rows t > Tstar (rows t <= Tstar were written by part A; disjoint)
  float4* out4 = (float4*)out;
  const size_t n4_bank = (size_t)T_STEPS * B_SZ * N_NEUR / 4;   // 16,777,216 (2^24)
  const size_t stride = (size_t)gridDim.x * blockDim.x;
  for (size_t i = (size_t)blockIdx.x * blockDim.x + threadIdx.x; i < n4_bank; i += stride) {
    if ((int)(i >> 14) > Tstar)   // 16384 float4 per timestep slab (B*N/4)
      out4[i] = make_float4(0.0f, 0.0f, 0.0f, 0.0f);
  }
}

extern "C" void kernel_launch(void* const* d_in, const int* in_sizes, int n_in,
                              void* d_out, int out_size, void* d_ws, size_t ws_size,
                              hipStream_t stream) {
  const float* x = (const float*)d_in[0];   // spike_seq [T,B,2] f32
  const float* W = (const float*)d_in[1];   // W [N,2] f32
  // d_in[2] (delays) unused: delays = 1..N strictly increasing -> winner = min active lane
  float* out = (float*)d_out;
  int* ws = (int*)d_ws;
  hipMemsetAsync(ws, 0x7F, 8, stream);      // ws[0..1] = SENT (graph-capturable)
  k_phase1<<<B_SZ,  64, 0, stream>>>(x, W, ws);
  k_finish<<<2048, 256, 0, stream>>>(x, W, ws, out);
}